// Round 5
// baseline (643.330 us; speedup 1.0000x reference)
//
#include <hip/hip_runtime.h>

// CTRNN: T=512, B=256, I=64, H=256.
//   pre = x_t @ W_in^T + b_in + h @ W_hh^T + b_hh + noise_t
//   h   = max(0.8*h + 0.2*pre, 0)
//
// R5: single fused persistent kernel. 256 blocks (1/batch) x 512 threads
// (8 waves, 2/SIMD -> 256-VGPR cap, vs the 128 cap that forced AGPR weight
// storage + per-FMA copy tax in R2/R4).
// Thread (g=tid>>6 in 0..7, jj=tid&63):
//   W_hh rows {jj+64m, m=0..3}, k in [32g,32g+32)  -> w[4][32], 128 VGPRs
//   W_in rows {jj+64m},        k in [ 8g, 8g+ 8)  -> wi[4][8],  32 VGPRs
// x_t is block-uniform: each wave scalar-loads its 8-float x chunk
// (readfirstlane-forced uniform address -> s_load, SGPR storage).
// h double-buffered in LDS (broadcast b128 reads, consumed in 16-float
// halves to cap peak pressure); partials pbuf[8][256] conflict-free;
// tid<256 reduce + leak/relu + coalesced store. 2 barriers/step.
// t-loop unrolled x2: compile-time LDS buffer index; x/noise prefetched
// 2 steps ahead (HBM-latency cover).
// RULES from R3/R4: private arrays ONLY const-indexed (full unroll);
// keep per-thread weight peak under the arch-VGPR cap or pay 2x VALU.

#define T_STEPS 512
#define BATCH   256
#define INSZ    64
#define HID     256
#define ALPHA_F 0.2f
#define OMA_F   0.8f

__global__ __launch_bounds__(512)
void ctrnn_fused(const float* __restrict__ x,       // [T, B, I]
                 const float* __restrict__ hidden,  // [B, H]
                 const float* __restrict__ noise,   // [T, H]
                 const float* __restrict__ W_in,    // [H, I]
                 const float* __restrict__ b_in,    // [H]
                 const float* __restrict__ W_hh,    // [H, H]
                 const float* __restrict__ b_hh,    // [H]
                 float* __restrict__ out)           // [T,B,H] ++ [B,H]
{
    const int tid = threadIdx.x;
    const int jj  = tid & 63;
    const int g   = tid >> 6;                        // 0..7, wave-uniform
    const int b   = blockIdx.x;
    const int gg  = __builtin_amdgcn_readfirstlane(g); // marked uniform

    __shared__ __align__(16) float hbuf[2][HID];
    __shared__ __align__(16) float pbuf[8][HID];

    // ---- Resident weights (fully const-indexed -> arch VGPRs) ----
    float w[4][32];
#pragma unroll
    for (int m = 0; m < 4; ++m) {
        const float* wr = &W_hh[(jj + 64 * m) * HID + 32 * g];
#pragma unroll
        for (int c = 0; c < 8; ++c) {
            float4 v = *reinterpret_cast<const float4*>(&wr[4 * c]);
            w[m][4*c+0] = v.x; w[m][4*c+1] = v.y;
            w[m][4*c+2] = v.z; w[m][4*c+3] = v.w;
        }
    }
    float wi[4][8];
#pragma unroll
    for (int m = 0; m < 4; ++m) {
        const float* wr = &W_in[(jj + 64 * m) * INSZ + 8 * g];
#pragma unroll
        for (int c = 0; c < 2; ++c) {
            float4 v = *reinterpret_cast<const float4*>(&wr[4 * c]);
            wi[m][4*c+0] = v.x; wi[m][4*c+1] = v.y;
            wi[m][4*c+2] = v.z; wi[m][4*c+3] = v.w;
        }
    }

    // ---- x chunks: wave-uniform scalar loads, 2 steps resident ----
    const float* xbase = x + (size_t)b * INSZ + 8 * gg;
    float xA[8], xB[8];
#pragma unroll
    for (int c = 0; c < 8; ++c) xA[c] = xbase[c];                        // t=0
#pragma unroll
    for (int c = 0; c < 8; ++c) xB[c] = xbase[(size_t)BATCH * INSZ + c]; // t=1

    // ---- per-row state (reduce threads: row r = tid) ----
    float hj = 0.f, bias = 0.f, nzA = 0.f, nzB = 0.f;
    if (tid < HID) {
        hj = hidden[b * HID + tid];
        hbuf[0][tid] = hj;
        bias = b_in[tid] + b_hh[tid];
        nzA = noise[tid];            // t=0
        nzB = noise[HID + tid];      // t=1
    }
    __syncthreads();

    const int koff = 32 * g;

    // One recurrence step with compile-time buffer index CUR.
    // acc computed from hbuf[CUR] + XR; h written to hbuf[CUR^1].
#define CTRNN_STEP(CUR, XR, NZ, TT)                                          \
    {                                                                        \
        float acc0 = 0.f, acc1 = 0.f, acc2 = 0.f, acc3 = 0.f;                \
        _Pragma("unroll")                                                    \
        for (int hh = 0; hh < 2; ++hh) {                                     \
            const int kb = koff + 16 * hh;                                   \
            float4 h0 = *reinterpret_cast<const float4*>(&hbuf[CUR][kb]);    \
            float4 h1 = *reinterpret_cast<const float4*>(&hbuf[CUR][kb+4]);  \
            float4 h2 = *reinterpret_cast<const float4*>(&hbuf[CUR][kb+8]);  \
            float4 h3 = *reinterpret_cast<const float4*>(&hbuf[CUR][kb+12]); \
            const int kw = 16 * hh;                                          \
            acc0 = fmaf(w[0][kw+0],  h0.x, acc0);                            \
            acc1 = fmaf(w[1][kw+0],  h0.x, acc1);                            \
            acc2 = fmaf(w[2][kw+0],  h0.x, acc2);                            \
            acc3 = fmaf(w[3][kw+0],  h0.x, acc3);                            \
            acc0 = fmaf(w[0][kw+1],  h0.y, acc0);                            \
            acc1 = fmaf(w[1][kw+1],  h0.y, acc1);                            \
            acc2 = fmaf(w[2][kw+1],  h0.y, acc2);                            \
            acc3 = fmaf(w[3][kw+1],  h0.y, acc3);                            \
            acc0 = fmaf(w[0][kw+2],  h0.z, acc0);                            \
            acc1 = fmaf(w[1][kw+2],  h0.z, acc1);                            \
            acc2 = fmaf(w[2][kw+2],  h0.z, acc2);                            \
            acc3 = fmaf(w[3][kw+2],  h0.z, acc3);                            \
            acc0 = fmaf(w[0][kw+3],  h0.w, acc0);                            \
            acc1 = fmaf(w[1][kw+3],  h0.w, acc1);                            \
            acc2 = fmaf(w[2][kw+3],  h0.w, acc2);                            \
            acc3 = fmaf(w[3][kw+3],  h0.w, acc3);                            \
            acc0 = fmaf(w[0][kw+4],  h1.x, acc0);                            \
            acc1 = fmaf(w[1][kw+4],  h1.x, acc1);                            \
            acc2 = fmaf(w[2][kw+4],  h1.x, acc2);                            \
            acc3 = fmaf(w[3][kw+4],  h1.x, acc3);                            \
            acc0 = fmaf(w[0][kw+5],  h1.y, acc0);                            \
            acc1 = fmaf(w[1][kw+5],  h1.y, acc1);                            \
            acc2 = fmaf(w[2][kw+5],  h1.y, acc2);                            \
            acc3 = fmaf(w[3][kw+5],  h1.y, acc3);                            \
            acc0 = fmaf(w[0][kw+6],  h1.z, acc0);                            \
            acc1 = fmaf(w[1][kw+6],  h1.z, acc1);                            \
            acc2 = fmaf(w[2][kw+6],  h1.z, acc2);                            \
            acc3 = fmaf(w[3][kw+6],  h1.z, acc3);                            \
            acc0 = fmaf(w[0][kw+7],  h1.w, acc0);                            \
            acc1 = fmaf(w[1][kw+7],  h1.w, acc1);                            \
            acc2 = fmaf(w[2][kw+7],  h1.w, acc2);                            \
            acc3 = fmaf(w[3][kw+7],  h1.w, acc3);                            \
            acc0 = fmaf(w[0][kw+8],  h2.x, acc0);                            \
            acc1 = fmaf(w[1][kw+8],  h2.x, acc1);                            \
            acc2 = fmaf(w[2][kw+8],  h2.x, acc2);                            \
            acc3 = fmaf(w[3][kw+8],  h2.x, acc3);                            \
            acc0 = fmaf(w[0][kw+9],  h2.y, acc0);                            \
            acc1 = fmaf(w[1][kw+9],  h2.y, acc1);                            \
            acc2 = fmaf(w[2][kw+9],  h2.y, acc2);                            \
            acc3 = fmaf(w[3][kw+9],  h2.y, acc3);                            \
            acc0 = fmaf(w[0][kw+10], h2.z, acc0);                            \
            acc1 = fmaf(w[1][kw+10], h2.z, acc1);                            \
            acc2 = fmaf(w[2][kw+10], h2.z, acc2);                            \
            acc3 = fmaf(w[3][kw+10], h2.z, acc3);                            \
            acc0 = fmaf(w[0][kw+11], h2.w, acc0);                            \
            acc1 = fmaf(w[1][kw+11], h2.w, acc1);                            \
            acc2 = fmaf(w[2][kw+11], h2.w, acc2);                            \
            acc3 = fmaf(w[3][kw+11], h2.w, acc3);                            \
            acc0 = fmaf(w[0][kw+12], h3.x, acc0);                            \
            acc1 = fmaf(w[1][kw+12], h3.x, acc1);                            \
            acc2 = fmaf(w[2][kw+12], h3.x, acc2);                            \
            acc3 = fmaf(w[3][kw+12], h3.x, acc3);                            \
            acc0 = fmaf(w[0][kw+13], h3.y, acc0);                            \
            acc1 = fmaf(w[1][kw+13], h3.y, acc1);                            \
            acc2 = fmaf(w[2][kw+13], h3.y, acc2);                            \
            acc3 = fmaf(w[3][kw+13], h3.y, acc3);                            \
            acc0 = fmaf(w[0][kw+14], h3.z, acc0);                            \
            acc1 = fmaf(w[1][kw+14], h3.z, acc1);                            \
            acc2 = fmaf(w[2][kw+14], h3.z, acc2);                            \
            acc3 = fmaf(w[3][kw+14], h3.z, acc3);                            \
            acc0 = fmaf(w[0][kw+15], h3.w, acc0);                            \
            acc1 = fmaf(w[1][kw+15], h3.w, acc1);                            \
            acc2 = fmaf(w[2][kw+15], h3.w, acc2);                            \
            acc3 = fmaf(w[3][kw+15], h3.w, acc3);                            \
        }                                                                    \
        _Pragma("unroll")                                                    \
        for (int c = 0; c < 8; ++c) {                                        \
            acc0 = fmaf(wi[0][c], XR[c], acc0);                              \
            acc1 = fmaf(wi[1][c], XR[c], acc1);                              \
            acc2 = fmaf(wi[2][c], XR[c], acc2);                              \
            acc3 = fmaf(wi[3][c], XR[c], acc3);                              \
        }                                                                    \
        pbuf[g][jj]       = acc0;                                            \
        pbuf[g][jj + 64]  = acc1;                                            \
        pbuf[g][jj + 128] = acc2;                                            \
        pbuf[g][jj + 192] = acc3;                                            \
        __syncthreads();                                                     \
        if (tid < HID) {                                                     \
            float s = bias + NZ;                                             \
            _Pragma("unroll")                                                \
            for (int q = 0; q < 8; ++q) s += pbuf[q][tid];                   \
            hj = fmaxf(fmaf(OMA_F, hj, ALPHA_F * s), 0.f);                   \
            out[((size_t)(TT) * BATCH + b) * HID + tid] = hj;                \
            hbuf[CUR ^ 1][tid] = hj;                                         \
        }                                                                    \
        __syncthreads();                                                     \
    }

#pragma unroll 1
    for (int t = 0; t < T_STEPS; t += 2) {
        // ---- even step t (reads hbuf[0], writes hbuf[1]) ----
        CTRNN_STEP(0, xA, nzA, t)
        // prefetch t+2 (consumed 2 steps from now -> full latency cover)
        if (t + 2 < T_STEPS) {
#pragma unroll
            for (int c = 0; c < 8; ++c)
                xA[c] = xbase[(size_t)(t + 2) * BATCH * INSZ + c];
            if (tid < HID) nzA = noise[(t + 2) * HID + tid];
        }
        // ---- odd step t+1 (reads hbuf[1], writes hbuf[0]) ----
        CTRNN_STEP(1, xB, nzB, t + 1)
        if (t + 3 < T_STEPS) {
#pragma unroll
            for (int c = 0; c < 8; ++c)
                xB[c] = xbase[(size_t)(t + 3) * BATCH * INSZ + c];
            if (tid < HID) nzB = noise[(t + 3) * HID + tid];
        }
    }
#undef CTRNN_STEP

    if (tid < HID) {
        out[(size_t)T_STEPS * BATCH * HID + (size_t)b * HID + tid] = hj;
    }
}

extern "C" void kernel_launch(void* const* d_in, const int* in_sizes, int n_in,
                              void* d_out, int out_size, void* d_ws, size_t ws_size,
                              hipStream_t stream) {
    const float* x      = (const float*)d_in[0];
    const float* hidden = (const float*)d_in[1];
    const float* noise  = (const float*)d_in[2];
    const float* W_in   = (const float*)d_in[3];
    const float* b_in   = (const float*)d_in[4];
    const float* W_hh   = (const float*)d_in[5];
    const float* b_hh   = (const float*)d_in[6];
    float* out = (float*)d_out;

    hipLaunchKernelGGL(ctrnn_fused, dim3(BATCH), dim3(512), 0, stream,
                       x, hidden, noise, W_in, b_in, W_hh, b_hh, out);
}